// Round 14
// baseline (113.151 us; speedup 1.0000x reference)
//
#include <hip/hip_runtime.h>
#include <math.h>

// MatchNet: 4-layer tanh MLP (6->20->20->20->8) + 150-iter PDHG QP solve.
// T=4 lanes/sample, pk-packed fp32, DPP-only cross-lane.
// R14: critical-cycle compression 22 -> ~16 hops.
//  - Gather S*v (not S*xbar): runs PARALLEL to the norm/rsq chain.
//  - State Swr = S*w updated off-chain: Swr' = Szr - scale*Svr (Szr const).
//  - l-update 2 hops after scale: l' = max(fma(scale, 2sig*Svr, H), 0),
//    H = fma(sig, Swr, l - sb) carried from previous iteration.
//  - v = fma(-TAU,sAB,svt) + fma(-TAU,gA3,q): q joins via parallel fma.
// All DPP gather patterns verbatim from R13 (proven): S^T*l on lA/lB;
// S-row patterns applied to v and (at init) to z and sv0.

#define NITERS 150

typedef float v2 __attribute__((ext_vector_type(2)));

__device__ __forceinline__ v2 vfma(v2 a, v2 b, v2 c) {
    return __builtin_elementwise_fma(a, b, c);
}
__device__ __forceinline__ v2 vmax(v2 a, v2 b) {
    return __builtin_elementwise_max(a, b);
}
#define LD2(W, off) (*(const v2*)((W) + (off)))

__device__ __forceinline__ float ftanh(float a) {
    float e = __expf(2.0f * a);
    return fmaf(-2.0f, __builtin_amdgcn_rcpf(e + 1.0f), 1.0f);
}

// quad_perm DPP; call unconditionally (R6 lesson); old=src (R13 win).
template<int P0, int P1, int P2, int P3>
__device__ __forceinline__ float qp(float x) {
    constexpr int ctrl = P0 | (P1 << 2) | (P2 << 4) | (P3 << 6);
    int xi = __builtin_bit_cast(int, x);
    int yi = __builtin_amdgcn_update_dpp(xi, xi, ctrl, 0xF, 0xF, true);
    return __builtin_bit_cast(float, yi);
}

#define FOR20(M) M(0) M(1) M(2) M(3) M(4) M(5) M(6) M(7) M(8) M(9) \
                 M(10) M(11) M(12) M(13) M(14) M(15) M(16) M(17) M(18) M(19)
#define FOR8(M)  M(0) M(1) M(2) M(3) M(4) M(5) M(6) M(7)

#define PK20(W, base, H) \
  ( vfma(LD2(W,(base)+0),H##0, vfma(LD2(W,(base)+4),H##2, vfma(LD2(W,(base)+8),H##4, \
      vfma(LD2(W,(base)+12),H##6, LD2(W,(base)+16)*H##8)))) \
  + vfma(LD2(W,(base)+2),H##1, vfma(LD2(W,(base)+6),H##3, vfma(LD2(W,(base)+10),H##5, \
      vfma(LD2(W,(base)+14),H##7, LD2(W,(base)+18)*H##9)))) )

#define PACK10(P, t) \
  v2 P##0 = {t##_0,  t##_1},  P##1 = {t##_2,  t##_3},  P##2 = {t##_4,  t##_5}; \
  v2 P##3 = {t##_6,  t##_7},  P##4 = {t##_8,  t##_9},  P##5 = {t##_10, t##_11}; \
  v2 P##6 = {t##_12, t##_13}, P##7 = {t##_14, t##_15}, P##8 = {t##_16, t##_17}; \
  v2 P##9 = {t##_18, t##_19};

// S-row gather (rows 0-3 -> A, rows 4,5 -> B on lanes 0,1), R13-verbatim
// patterns; input: per-lane pair (aA = comp g, aB = comp g+4).
#define SROW_GATHER(aA, aB, outA, outB, g_) \
    float h1_ = qp<0,1,2,0>(aA); \
    float h2a_ = qp<3,3,0,0>(aA); \
    float h2b_ = qp<0,0,0,0>(aB); \
    float h2_ = ((g_) < 2) ? h2a_ : h2b_; \
    float h3_ = qp<1,2,3,1>(aB); \
    float outA = (h1_ + h2_) + h3_; \
    float k1_ = qp<1,2,0,0>(aA); \
    float k2a_ = qp<0,3,0,0>(aA); \
    float k2b_ = qp<2,0,0,0>(aB); \
    float k2_ = ((g_) == 1) ? k2a_ : k2b_; \
    float k3_ = qp<3,0,0,0>(aB); \
    float outB = (k1_ + k2_) + k3_;

__global__ __launch_bounds__(256, 2)
void matchnet_kernel(
    const float* __restrict__ X,
    const float* __restrict__ W1, const float* __restrict__ b1,
    const float* __restrict__ W2, const float* __restrict__ b2,
    const float* __restrict__ W3, const float* __restrict__ b3,
    const float* __restrict__ W4, const float* __restrict__ b4,
    float* __restrict__ out, int B)
{
    const int tid = blockIdx.x * 256 + threadIdx.x;
    const int s   = tid >> 2;       // sample
    if (s >= B) return;
    const int g   = tid & 3;        // quad lane

    const float TAU = 0.9f / sqrtf(26.0f);
    const float SIG = TAU;
    const float TS  = TAU * SIG;
    const float SIG2 = 2.0f * SIG;

    // ---- load sample ----
    float zin0, zin1, zin2, zin3, zin4, zin5;
    v2 zin01, zin23, zin45;
    {
        const float2* xp = (const float2*)(X + (size_t)s * 6);
        float2 p0 = xp[0], p1 = xp[1], p2 = xp[2];
        zin0 = p0.x; zin1 = p0.y; zin2 = p1.x;
        zin3 = p1.y; zin4 = p2.x; zin5 = p2.y;
        zin01 = (v2){p0.x, p0.y}; zin23 = (v2){p1.x, p1.y}; zin45 = (v2){p2.x, p2.y};
    }

    // ---- MLP (redundant across 4 lanes; K-dim pk-packed) ----
#define L1R(j) float t1_##j; { \
        v2 r_ = vfma(LD2(W1,(j)*6+0), zin01, vfma(LD2(W1,(j)*6+2), zin23, LD2(W1,(j)*6+4)*zin45)); \
        t1_##j = ftanh(b1[j] + (r_.x + r_.y)); }
    FOR20(L1R)
    PACK10(A, t1)
#define L2R(j) float t2_##j; { \
        v2 r_ = PK20(W2, (j)*20, A); \
        t2_##j = ftanh(b2[j] + (r_.x + r_.y)); }
    FOR20(L2R)
    PACK10(Bh, t2)
#define L3R(j) float t3_##j; { \
        v2 r_ = PK20(W3, (j)*20, Bh); \
        t3_##j = ftanh(b3[j] + (r_.x + r_.y)); }
    FOR20(L3R)
    PACK10(C, t3)
#define ZR(j) float z##j; { \
        v2 r_ = PK20(W4, (j)*20, C); \
        z##j = ftanh(b4[j] + (r_.x + r_.y)); }
    FOR8(ZR)

    // ---- per-lane selects: zA = z_g, zB = z_{4+g}, sbA/sbB ----
    const bool b0 = (g & 1), b1_ = (g & 2);
    float z01 = b0 ? z1 : z0,  z23 = b0 ? z3 : z2;
    float zA  = b1_ ? z23 : z01;
    float z45 = b0 ? z5 : z4,  z67 = b0 ? z7 : z6;
    float zB  = b1_ ? z67 : z45;

    float i01 = b0 ? zin1 : zin0, i23 = b0 ? zin3 : zin2;
    float igA = b1_ ? i23 : i01;            // zin_g
    float i45 = b0 ? zin5 : zin4;           // zin_{4+g} for g<2
    float sbA = SIG * igA;
    float sbB = (g < 2) ? SIG * i45 : 1e30f;  // 1e30 pins dummy l1B to 0

    // ---- PDHG state ----
    // sv = x - z (post-prox step), svt = sv + TAU, q = TAU*l2, w = 2z - x,
    // lA/lB = l1 duals, Swr = S*w (row-gathered, per-lane constraint slot),
    // H = fma(SIG, Swr, l - sb) carried.
    v2 zv = {zA, zB};
    v2 sv = {fmaxf(zA, 0.0f) - zA, fmaxf(zB, 0.0f) - zB};   // x0 - z
    v2 svt = {sv.x + TAU, sv.y + TAU};
    v2 q  = {0.0f, 0.0f};
    v2 w  = {zv.x - sv.x, zv.y - sv.y};                     // 2z - x0
    float lA = 0.0f, lB = 0.0f;

    // Szr = S*z rows (const); Ssv0 = S*sv0 rows; Swr0 = Szr - Ssv0
    float SzrA, SzrB, Ssv0A, Ssv0B;
    { SROW_GATHER(zA, zB, oA, oB, g)  SzrA = oA; SzrB = oB; }
    { SROW_GATHER(sv.x, sv.y, oA, oB, g)  Ssv0A = oA; Ssv0B = oB; }
    float SwrA = SzrA - Ssv0A, SwrB = SzrB - Ssv0B;
    float HA = fmaf(SIG, SwrA, -sbA);
    float HB = fmaf(SIG, SwrB, -sbB);

    const v2 vTAU  = {TAU, TAU};
    const v2 vmTS  = {-TS, -TS};
    const v2 vTWO  = {2.0f, 2.0f};
    const v2 vZERO = {0.0f, 0.0f};

#pragma unroll 1
    for (int it = 0; it < NITERS; ++it) {
        // ---- st = S^T l1 (R13-verbatim DPP gathers on lA,lB) ----
        float gA1  = qp<0,1,2,0>(lA);
        float gA2a = qp<3,0,0,1>(lA);
        float gA2b = qp<0,0,1,0>(lB);
        float gA2  = ((g == 0) || (g == 3)) ? gA2a : gA2b;
        float gA3  = qp<2,2,2,1>(lB);
        float sABA = gA1 + gA2;
        float gB1  = qp<2,0,1,2>(lA);
        float gB2a = qp<3,3,0,0>(lA);
        float gB2b = qp<0,0,0,0>(lB);
        float gB2  = (g < 2) ? gB2a : gB2b;
        float gB3  = qp<1,2,2,2>(lB);
        float sABB = gB1 + gB2;

        // v = (svt - TAU*sAB) + (q - TAU*g3): two parallel fmas + add
        float vA = fmaf(-TAU, sABA, svt.x) + fmaf(-TAU, gA3, q.x);
        float vB = fmaf(-TAU, sABB, svt.y) + fmaf(-TAU, gB3, q.y);
        v2 v = {vA, vB};

        // ---- Svr = S*v rows (parallel with norm chain) ----
        SROW_GATHER(vA, vB, SvrA, SvrB, g)
        float GA = SIG2 * SvrA;
        float GB = SIG2 * SvrB;

        // ---- ||v||^2 over quad ----
        v2 sq = v * v;
        float nl = sq.x + sq.y;
        nl = nl + qp<1,0,3,2>(nl);
        nl = nl + qp<2,3,0,1>(nl);
        float scale = fmaxf(fmaf(-TAU, __builtin_amdgcn_rsqf(nl), 1.0f), 0.0f);

        // ---- l1 update: 2 hops after scale ----
        lA = fmaxf(fmaf(scale, GA, HA), 0.0f);
        lB = fmaxf(fmaf(scale, GB, HB), 0.0f);  // lanes 2,3 clamp to 0

        // ---- off-chain state refresh ----
        SwrA = fmaf(-scale, SvrA, SzrA);        // S*w' = S*z - scale*S*v
        SwrB = fmaf(-scale, SvrB, SzrB);
        HA = fmaf(SIG, SwrA, lA - sbA);
        HB = fmaf(SIG, SwrB, lB - sbB);

        // ---- primal updates (pk) ----
        v2 vs = {scale, scale};
        v2 svn = vs * v;                        // x_new - z
        v2 xb  = vfma(vTWO, svn, w);            // 2*x_new - x_old
        w  = zv - svn;                          // 2z - x_new
        q  = vmax(vfma(vmTS, xb, q), vZERO);    // TAU*l2'
        sv = svn;
        svt = svn + vTAU;
    }

    // x = 2z - w
    out[(size_t)s * 8 + g]     = zA + zA - w.x;
    out[(size_t)s * 8 + 4 + g] = zB + zB - w.y;
}

extern "C" void kernel_launch(void* const* d_in, const int* in_sizes, int n_in,
                              void* d_out, int out_size, void* d_ws, size_t ws_size,
                              hipStream_t stream) {
    const float* X  = (const float*)d_in[0];
    const float* W1 = (const float*)d_in[1];
    const float* b1 = (const float*)d_in[2];
    const float* W2 = (const float*)d_in[3];
    const float* b2 = (const float*)d_in[4];
    const float* W3 = (const float*)d_in[5];
    const float* b3 = (const float*)d_in[6];
    const float* W4 = (const float*)d_in[7];
    const float* b4 = (const float*)d_in[8];
    float* out = (float*)d_out;
    const int B = in_sizes[0] / 6;
    const int threads = B * 4;
    const int blocks = (threads + 255) / 256;
    hipLaunchKernelGGL(matchnet_kernel, dim3(blocks), dim3(256), 0, stream,
                       X, W1, b1, W2, b2, W3, b3, W4, b4, out, B);
}